// Round 8
// baseline (88.943 us; speedup 1.0000x reference)
//
#include <hip/hip_runtime.h>

#define BINS 10
#define BLOCK 256
#define GRID 2048

#define LOG2E 1.44269504088896340736f
#define LN2   0.69314718055994530942f

// ---------------------------------------------------------------------------
// For logit x with one-hot target bit tg, let y = tg ? -x : x. Then
//   g   = |sigmoid(x) - tg| = sigmoid(y)
//   bce = softplus(y) = ln(1 + e^y)
// bin(g) >= k  <=>  y >= logit(k/10).  Accumulate CUMULATIVE stats per
// threshold in registers; counts via ballot+popcount (SALU pipe). Per-bin
// values are neighbor differences taken in the last block's finalize.
//
// ws layout (doubles):
//   [0..9]   S_0..S_9   cumulative bce sums  (S_0 = all logits)
//   [10..18] C_1..C_9   cumulative counts    (C_0 = 2N known analytically)
//   [32]     arrival counter (as unsigned, low word)
// All ws accesses are device-scope atomics -> coherent across XCDs.
// ghmc_init re-zeros every call (harness poisons ws once, never re-poisons).
// ---------------------------------------------------------------------------

__constant__ const float THR[9] = {
    -2.1972246f, -1.3862944f, -0.84729785f, -0.40546511f, 0.0f,
     0.40546511f, 0.84729785f, 1.3862944f,  2.1972246f };

__global__ void ghmc_init(double* ws) {
    int i = threadIdx.x;
    if (i < 33) ws[i] = 0.0;   // sums, counts, counter (bit-zero == 0u)
}

__device__ __forceinline__ void proc(float y, float* __restrict__ s,
                                     unsigned* __restrict__ c) {
    y = fminf(fmaxf(y, -80.0f), 80.0f);              // v_med3_f32 guard
    float u  = __builtin_amdgcn_exp2f(y * LOG2E);    // e^y
    float d  = 1.0f + u;
    float lg = __builtin_amdgcn_logf(d);             // log2(1+u)
    float sp = lg * LN2;                             // softplus(y) = bce
    s[0] += sp;
#pragma unroll
    for (int k = 0; k < 9; ++k) {
        bool cond = y >= THR[k];
        c[k] += (unsigned)__popcll(__ballot(cond));  // SALU: s_bcnt1 + s_add
        s[k + 1] += cond ? sp : 0.0f;                // v_cndmask + v_add
    }
}

__device__ __forceinline__ void proc_row(float x0, float x1, int t,
                                         float* __restrict__ s,
                                         unsigned* __restrict__ c) {
    // class0 flips iff t==0, class1 flips iff t==1 (t in {0,1})
    unsigned s0 = (unsigned)(t ^ 1) << 31;
    unsigned s1 = s0 ^ 0x80000000u;
    proc(__uint_as_float(__float_as_uint(x0) ^ s0), s, c);
    proc(__uint_as_float(__float_as_uint(x1) ^ s1), s, c);
}

__global__ __launch_bounds__(BLOCK, 8) void ghmc_main(
    const float4* __restrict__ pred4,   // one float4 = 2 rows' logits
    const int4*   __restrict__ tgt4,    // one int4   = 4 rows' targets (int32)
    double* __restrict__ wsd,
    float* __restrict__ out,
    int nQuads, int nRows)
{
    const int tid = threadIdx.x;
    float    s[BINS];      // cumulative bce sums, per-lane registers
    unsigned c[9];         // cumulative counts per threshold, wave-uniform SGPRs
#pragma unroll
    for (int b = 0; b < BINS; ++b) s[b] = 0.0f;
#pragma unroll
    for (int k = 0; k < 9; ++k) c[k] = 0u;

    for (int i = blockIdx.x * BLOCK + tid; i < nQuads; i += GRID * BLOCK) {
        float4 pa = pred4[2 * i + 0];   // rows 4i, 4i+1
        float4 pb = pred4[2 * i + 1];   // rows 4i+2, 4i+3
        int4   tq = tgt4[i];
        proc_row(pa.x, pa.y, tq.x, s, c);
        proc_row(pa.z, pa.w, tq.y, s, c);
        proc_row(pb.x, pb.y, tq.z, s, c);
        proc_row(pb.z, pb.w, tq.w, s, c);
    }

    // defensive scalar tail (N divisible by 4 here)
    if (blockIdx.x == 0 && tid == 0) {
        const float* pf = (const float*)pred4;
        const int*   tf = (const int*)tgt4;
        for (int r = nQuads * 4; r < nRows; ++r)
            proc_row(pf[2 * r], pf[2 * r + 1], tf[r], s, c);
    }

    // wave-level shuffle reduce of the per-lane sums (counts already uniform)
#pragma unroll
    for (int off = 32; off > 0; off >>= 1) {
#pragma unroll
        for (int b = 0; b < BINS; ++b) s[b] += __shfl_down(s[b], off, 64);
    }

    __shared__ float    sred[4][BINS];
    __shared__ unsigned cred[4][9];
    const int wid  = tid >> 6;
    const int lane = tid & 63;
    if (lane == 0) {
#pragma unroll
        for (int b = 0; b < BINS; ++b) sred[wid][b] = s[b];
#pragma unroll
        for (int k = 0; k < 9; ++k) cred[wid][k] = c[k];
    }
    __syncthreads();

    // 19 device-scope double atomics per block (order-noise ~1e-16: OK)
    if (tid < BINS) {
        float S = sred[0][tid] + sred[1][tid] + sred[2][tid] + sred[3][tid];
        atomicAdd(&wsd[tid], (double)S);
    } else if (tid >= 16 && tid < 25) {
        int k = tid - 16;
        unsigned C = cred[0][k] + cred[1][k] + cred[2][k] + cred[3][k];
        atomicAdd(&wsd[10 + k], (double)C);
    }
    __syncthreads();   // drains this block's atomics (vmcnt(0) before barrier)

    __shared__ unsigned is_last;
    if (tid == 0) {
        __threadfence();
        unsigned* ctr = (unsigned*)(wsd + 32);
        unsigned old = atomicAdd(ctr, 1u);
        is_last = (old == (unsigned)(GRID - 1)) ? 1u : 0u;
    }
    __syncthreads();

    if (is_last) {
        // last arriving block: all other blocks' atomics are complete.
        __shared__ double vals[19];
        if (tid < 19) vals[tid] = atomicAdd(&wsd[tid], 0.0);  // coherent read
        __syncthreads();
        if (tid == 0) {
            double C[BINS + 1], S[BINS + 1];
            double tot = 2.0 * (double)nRows;   // C_0: every logit counted
            C[0] = tot;
#pragma unroll
            for (int k = 1; k <= 9; ++k) C[k] = vals[9 + k];
            C[BINS] = 0.0;
#pragma unroll
            for (int b = 0; b < BINS; ++b) S[b] = vals[b];
            S[BINS] = 0.0;
            int nz = 0;
            double acc = 0.0;
#pragma unroll
            for (int b = 0; b < BINS; ++b) {
                double cnt = C[b] - C[b + 1];
                double sm  = S[b] - S[b + 1];
                if (cnt > 0.0) { nz++; acc += sm / cnt; }
            }
            out[0] = (float)((nz > 0) ? (acc / (double)nz) : 0.0);
        }
    }
}

extern "C" void kernel_launch(void* const* d_in, const int* in_sizes, int n_in,
                              void* d_out, int out_size, void* d_ws, size_t ws_size,
                              hipStream_t stream) {
    const float* pred = (const float*)d_in[0];   // [N,2] float32
    const int* target = (const int*)d_in[1];     // [N] int32 (harness lowers int64)
    const int nRows = in_sizes[1];
    const int nQuads = nRows / 4;
    double* wsd = (double*)d_ws;
    float* out = (float*)d_out;

    ghmc_init<<<1, 64, 0, stream>>>(wsd);
    ghmc_main<<<GRID, BLOCK, 0, stream>>>(
        (const float4*)pred, (const int4*)target, wsd, out, nQuads, nRows);
}

// Round 9
// 33.338 us; speedup vs baseline: 2.6679x; 2.6679x over previous
//
#include <hip/hip_runtime.h>

#define BINS 10
#define BLOCK 256
#define GRID 2048
#define NCOPY 8            // atomic striping factor
#define CSTRIDE 32         // doubles per copy (256 B -> distinct cache lines)

#define LOG2E 1.44269504088896340736f
#define LN2   0.6931471805599453094

// ---------------------------------------------------------------------------
// For logit x with one-hot target bit tg, let y = tg ? -x : x. Then
//   g   = |sigmoid(x) - tg| = sigmoid(y)
//   bce = softplus(y) = ln(1 + e^y) = ln2 * log2(1 + e^y)
// bin(g) >= k  <=>  y >= logit(k/10).  Accumulate CUMULATIVE stats per
// threshold in registers (sums kept in log2 units; *ln2 once at the end);
// counts via ballot+popcount on the SALU pipe. Per-bin values are neighbor
// differences, taken in the tiny finalize kernel.
//
// ws: double[NCOPY][CSTRIDE]; copy r, entries [0..9] = S_0..S_9 (log2 units),
// [10..18] = C_1..C_9. Blocks atomically add into copy (blockIdx & 7) ->
// per-address serialization is GRID/NCOPY = 256, not 2048. No fences: the
// kernel boundary orders main's atomics before fin's plain loads.
// ---------------------------------------------------------------------------

__constant__ const float THR[9] = {
    -2.1972246f, -1.3862944f, -0.84729785f, -0.40546511f, 0.0f,
     0.40546511f, 0.84729785f, 1.3862944f,  2.1972246f };

__global__ void ghmc_init(double* ws) {
    int i = threadIdx.x;
    if (i < NCOPY * CSTRIDE) ws[i] = 0.0;
}

__device__ __forceinline__ void proc(float y, float* __restrict__ s,
                                     unsigned* __restrict__ c) {
    y = fminf(fmaxf(y, -80.0f), 80.0f);              // v_med3_f32 guard
    float u  = __builtin_amdgcn_exp2f(y * LOG2E);    // e^y
    float d  = 1.0f + u;
    float lg = __builtin_amdgcn_logf(d);             // log2(1+u) = bce/ln2
    s[0] += lg;
#pragma unroll
    for (int k = 0; k < 9; ++k) {
        bool cond = y >= THR[k];
        c[k] += (unsigned)__popcll(__ballot(cond));  // SALU: s_bcnt1 + s_add
        s[k + 1] += cond ? lg : 0.0f;                // v_cndmask + v_add
    }
}

__device__ __forceinline__ void proc_row(float x0, float x1, int t,
                                         float* __restrict__ s,
                                         unsigned* __restrict__ c) {
    // class0 flips iff t==0, class1 flips iff t==1 (t in {0,1})
    unsigned s0 = (unsigned)(t ^ 1) << 31;
    unsigned s1 = s0 ^ 0x80000000u;
    proc(__uint_as_float(__float_as_uint(x0) ^ s0), s, c);
    proc(__uint_as_float(__float_as_uint(x1) ^ s1), s, c);
}

__global__ __launch_bounds__(BLOCK, 8) void ghmc_main(
    const float4* __restrict__ pred4,   // one float4 = 2 rows' logits
    const int4*   __restrict__ tgt4,    // one int4   = 4 rows' targets (int32)
    double* __restrict__ wsd,
    int nQuads, int nRows)
{
    const int tid = threadIdx.x;
    float    s[BINS];      // cumulative log2-bce sums, per-lane registers
    unsigned c[9];         // cumulative counts per threshold, wave-uniform SGPRs
#pragma unroll
    for (int b = 0; b < BINS; ++b) s[b] = 0.0f;
#pragma unroll
    for (int k = 0; k < 9; ++k) c[k] = 0u;

    for (int i = blockIdx.x * BLOCK + tid; i < nQuads; i += GRID * BLOCK) {
        float4 pa = pred4[2 * i + 0];   // rows 4i, 4i+1
        float4 pb = pred4[2 * i + 1];   // rows 4i+2, 4i+3
        int4   tq = tgt4[i];
        proc_row(pa.x, pa.y, tq.x, s, c);
        proc_row(pa.z, pa.w, tq.y, s, c);
        proc_row(pb.x, pb.y, tq.z, s, c);
        proc_row(pb.z, pb.w, tq.w, s, c);
    }

    // defensive scalar tail (N divisible by 4 here)
    if (blockIdx.x == 0 && tid == 0) {
        const float* pf = (const float*)pred4;
        const int*   tf = (const int*)tgt4;
        for (int r = nQuads * 4; r < nRows; ++r)
            proc_row(pf[2 * r], pf[2 * r + 1], tf[r], s, c);
    }

    // wave-level shuffle reduce of the per-lane sums (counts already uniform)
#pragma unroll
    for (int off = 32; off > 0; off >>= 1) {
#pragma unroll
        for (int b = 0; b < BINS; ++b) s[b] += __shfl_down(s[b], off, 64);
    }

    __shared__ float    sred[4][BINS];
    __shared__ unsigned cred[4][9];
    const int wid  = tid >> 6;
    const int lane = tid & 63;
    if (lane == 0) {
#pragma unroll
        for (int b = 0; b < BINS; ++b) sred[wid][b] = s[b];
#pragma unroll
        for (int k = 0; k < 9; ++k) cred[wid][k] = c[k];
    }
    __syncthreads();

    // 19 device atomics per block, striped over 8 copies (256-deep per addr)
    double* wcopy = wsd + (blockIdx.x & (NCOPY - 1)) * CSTRIDE;
    if (tid < BINS) {
        float S = sred[0][tid] + sred[1][tid] + sred[2][tid] + sred[3][tid];
        atomicAdd(&wcopy[tid], (double)S);
    } else if (tid >= 16 && tid < 25) {
        int k = tid - 16;
        unsigned C = cred[0][k] + cred[1][k] + cred[2][k] + cred[3][k];
        atomicAdd(&wcopy[10 + k], (double)C);
    }
    // no fence, no readback: kernel boundary is the release point
}

__global__ __launch_bounds__(64) void ghmc_fin(
    const double* __restrict__ wsd, float* __restrict__ out, int nRows)
{
    const int tid = threadIdx.x;
    __shared__ double vals[19];
    if (tid < 19) {
        double a = 0.0;
#pragma unroll
        for (int r = 0; r < NCOPY; ++r) a += wsd[r * CSTRIDE + tid];
        vals[tid] = a;
    }
    __syncthreads();
    if (tid == 0) {
        double C[BINS + 1], S[BINS + 1];
        C[0] = 2.0 * (double)nRows;          // C_0: every logit counted
#pragma unroll
        for (int k = 1; k <= 9; ++k) C[k] = vals[9 + k];
        C[BINS] = 0.0;
#pragma unroll
        for (int b = 0; b < BINS; ++b) S[b] = vals[b];
        S[BINS] = 0.0;
        int nz = 0;
        double acc = 0.0;
#pragma unroll
        for (int b = 0; b < BINS; ++b) {
            double cnt = C[b] - C[b + 1];
            double sm  = (S[b] - S[b + 1]) * LN2;   // log2 units -> nats
            if (cnt > 0.0) { nz++; acc += sm / cnt; }
        }
        out[0] = (float)((nz > 0) ? (acc / (double)nz) : 0.0);
    }
}

extern "C" void kernel_launch(void* const* d_in, const int* in_sizes, int n_in,
                              void* d_out, int out_size, void* d_ws, size_t ws_size,
                              hipStream_t stream) {
    const float* pred = (const float*)d_in[0];   // [N,2] float32
    const int* target = (const int*)d_in[1];     // [N] int32 (harness lowers int64)
    const int nRows = in_sizes[1];
    const int nQuads = nRows / 4;
    double* wsd = (double*)d_ws;
    float* out = (float*)d_out;

    ghmc_init<<<1, 256, 0, stream>>>(wsd);
    ghmc_main<<<GRID, BLOCK, 0, stream>>>(
        (const float4*)pred, (const int4*)target, wsd, nQuads, nRows);
    ghmc_fin<<<1, 64, 0, stream>>>(wsd, out, nRows);
}